// Round 2
// baseline (83.031 us; speedup 1.0000x reference)
//
#include <hip/hip_runtime.h>
#include <hip/hip_bf16.h>

// LinkPredictor: q[i,j] = relu(z_i@W1a + z_j@W1b + b1) @ W2 + b2, N=1024, D=128.
// All inputs/outputs are fp32 per the reference (NaN post-mortem R1: bf16 cast
// of fp32 buffers produced NaN; contract says float32 -> const float*).
// Stage 1: pic = z@W1[:D] + b1, pj = z@W1[D:]  (fp32, in d_ws, 1 MB).
// Stage 2: per 64x64 pair tile, LDS-staged fp32, 4x4 register micro-tile.

#define NN 1024
#define DD 128
#define TI 64
#define TJ 64
#define PAD 132   // LDS row pitch in floats: stride PAD -> banks step 4 -> 2-way alias (free, m136)

__global__ __launch_bounds__(256) void proj_kernel(
    const float* __restrict__ z,
    const float* __restrict__ W1,
    const float* __restrict__ b1,
    float* __restrict__ pic,
    float* __restrict__ pj)
{
    __shared__ float zs[DD];
    const int i = blockIdx.x;
    const int t = threadIdx.x;
    if (t < DD) zs[t] = z[i * DD + t];
    __syncthreads();

    const int half = t >> 7;          // 0 -> pic (W1 top half), 1 -> pj (W1 bottom half)
    const int d = t & (DD - 1);
    const float* Wcol = W1 + half * DD * DD + d;

    float acc = 0.f;
    #pragma unroll 16
    for (int k = 0; k < DD; ++k)
        acc = fmaf(zs[k], Wcol[k * DD], acc);

    if (half == 0)
        pic[i * DD + d] = acc + b1[d];   // fold bias into pic
    else
        pj[i * DD + d] = acc;
}

__global__ __launch_bounds__(256) void pair_kernel(
    const float* __restrict__ pic,
    const float* __restrict__ pj,
    const float* __restrict__ W2,
    const float* __restrict__ b2,
    float* __restrict__ out)
{
    __shared__ float a_s[TI * PAD];
    __shared__ float b_s[TJ * PAD];
    __shared__ float w_s[DD];

    const int t  = threadIdx.x;
    const int bi = blockIdx.x;
    const int bj = blockIdx.y;

    // Stage tiles: 64 rows x 128 floats = 2048 float4 each; 8 per thread, coalesced.
    const float4* srcA = (const float4*)(pic + bi * TI * DD);
    const float4* srcB = (const float4*)(pj + bj * TJ * DD);
    #pragma unroll
    for (int u = 0; u < 8; ++u) {
        int f   = t + 256 * u;     // [0, 2048)
        int row = f >> 5;          // 32 float4 per row
        int c4  = f & 31;
        float4 va = srcA[f];
        float4 vb = srcB[f];
        *(float4*)&a_s[row * PAD + c4 * 4] = va;
        *(float4*)&b_s[row * PAD + c4 * 4] = vb;
    }
    if (t < DD) w_s[t] = W2[t];
    __syncthreads();

    const int tx = t & 15;   // j-lane
    const int ty = t >> 4;   // i-lane
    // Interleaved ownership: i = bi*64 + ty + 16*ii, j = bj*64 + tx + 16*jj.
    // Consecutive tx -> LDS stride PAD floats -> banks step 4: 2-way alias only (free).
    const float* ap = a_s + ty * PAD;
    const float* bp = b_s + tx * PAD;

    float acc[4][4];
    #pragma unroll
    for (int ii = 0; ii < 4; ++ii)
        #pragma unroll
        for (int jj = 0; jj < 4; ++jj) acc[ii][jj] = 0.f;

    #pragma unroll 2
    for (int d = 0; d < DD; d += 4) {
        float4 w4 = *(const float4*)(w_s + d);
        float4 av[4], bv[4];
        #pragma unroll
        for (int ii = 0; ii < 4; ++ii) av[ii] = *(const float4*)(ap + ii * 16 * PAD + d);
        #pragma unroll
        for (int jj = 0; jj < 4; ++jj) bv[jj] = *(const float4*)(bp + jj * 16 * PAD + d);

        #pragma unroll
        for (int ii = 0; ii < 4; ++ii) {
            const float ax = av[ii].x, ay = av[ii].y, az = av[ii].z, aw = av[ii].w;
            #pragma unroll
            for (int jj = 0; jj < 4; ++jj) {
                acc[ii][jj] = fmaf(fmaxf(ax + bv[jj].x, 0.f), w4.x, acc[ii][jj]);
                acc[ii][jj] = fmaf(fmaxf(ay + bv[jj].y, 0.f), w4.y, acc[ii][jj]);
                acc[ii][jj] = fmaf(fmaxf(az + bv[jj].z, 0.f), w4.z, acc[ii][jj]);
                acc[ii][jj] = fmaf(fmaxf(aw + bv[jj].w, 0.f), w4.w, acc[ii][jj]);
            }
        }
    }

    const float bb = b2[0];
    #pragma unroll
    for (int ii = 0; ii < 4; ++ii) {
        const int i = bi * TI + ty + ii * 16;
        #pragma unroll
        for (int jj = 0; jj < 4; ++jj) {
            const int j = bj * TJ + tx + jj * 16;
            out[(size_t)i * NN + j] = acc[ii][jj] + bb;
        }
    }
}

extern "C" void kernel_launch(void* const* d_in, const int* in_sizes, int n_in,
                              void* d_out, int out_size, void* d_ws, size_t ws_size,
                              hipStream_t stream)
{
    const float* z  = (const float*)d_in[0];   // [1024,128]
    const float* W1 = (const float*)d_in[1];   // [256,128] row-major
    const float* b1 = (const float*)d_in[2];   // [128]
    const float* W2 = (const float*)d_in[3];   // [128]
    const float* b2 = (const float*)d_in[4];   // [1]
    float* out = (float*)d_out;                // [1024*1024]

    float* pic = (float*)d_ws;                 // [1024,128] fp32 (bias folded)
    float* pj  = pic + NN * DD;                // [1024,128] fp32

    proj_kernel<<<NN, 256, 0, stream>>>(z, W1, b1, pic, pj);

    dim3 grid(NN / TI, NN / TJ);
    pair_kernel<<<grid, 256, 0, stream>>>(pic, pj, W2, b2, out);
}